// Round 7
// baseline (9391.515 us; speedup 1.0000x reference)
//
#include <hip/hip_runtime.h>

typedef __attribute__((ext_vector_type(8))) short short8;
typedef __attribute__((ext_vector_type(4))) float float4_t;
typedef unsigned short u16;
typedef unsigned int u32;
typedef unsigned long long u64;

// B=256, T=256, IN=128, S=1024. Phases m=0..511 (stage=m&1, t=m>>1).
// 4 independent 64-row chains, time-multiplexed: slot k (0..2047) = chain k&3, phase k>>2.
// State words tagged (bf16<<16)|phase — dword-atomic, self-validating, init-free.

__device__ __forceinline__ u16 f2bf(float f) {
  u32 u = __builtin_bit_cast(u32, f);
  u += 0x7fffu + ((u >> 16) & 1u);          // RNE
  return (u16)(u >> 16);
}
__device__ __forceinline__ float bf2f(u16 h) {
  u32 u = ((u32)h) << 16;
  return __builtin_bit_cast(float, u);
}
__device__ __forceinline__ short8 cvt8(float4_t f0, float4_t f1) {
  short8 v;
  v[0]=(short)f2bf(f0[0]); v[1]=(short)f2bf(f0[1]); v[2]=(short)f2bf(f0[2]); v[3]=(short)f2bf(f0[3]);
  v[4]=(short)f2bf(f1[0]); v[5]=(short)f2bf(f1[1]); v[6]=(short)f2bf(f1[2]); v[7]=(short)f2bf(f1[3]);
  return v;
}

__global__ __launch_bounds__(256) void prep_w(const float* __restrict__ Wr,
                                              const float* __restrict__ Wr2,
                                              const float* __restrict__ Win,
                                              u16* __restrict__ W1b,
                                              u16* __restrict__ W2b,
                                              u16* __restrict__ Winb) {
  const int i = blockIdx.x * 256 + threadIdx.x;   // 0 .. 1048575
  W1b[i] = f2bf(Wr[i]);
  W2b[i] = f2bf(Wr2[i]);
  if (i < 131072) Winb[i] = f2bf(Win[i]);
}

// ext GEMM: ebuf[t][b][n] = sum_k x[b][t][k]*Winb[n][k] + bin[n], bf16 out.
// WG = 64 rows x all 1024 cols; x read once; Winb pre-converted bf16.
__global__ __launch_bounds__(256) void ext_gemm(const float* __restrict__ x,
                                                const u16* __restrict__ Winb,
                                                const float* __restrict__ bin,
                                                u16* __restrict__ ebuf) {
  const int mt = blockIdx.x;                      // 0..1023
  const int tid = threadIdx.x;
  const int wave = tid >> 6, lane = tid & 63, quad = lane >> 4, lm = lane & 15;
  const int m0 = (mt << 6) + (wave << 4);

  short8 a[4];
#pragma unroll
  for (int ks = 0; ks < 4; ++ks) {
    const float* p = x + (m0 + lm) * 128 + (ks * 32 + quad * 8);
    a[ks] = cvt8(*(const float4_t*)p, *(const float4_t*)(p + 4));
  }
  for (int nt = 0; nt < 16; ++nt) {
    const int n0 = nt << 6;
    short8 bfr[4][4];
#pragma unroll
    for (int nsub = 0; nsub < 4; ++nsub)
#pragma unroll
      for (int ks = 0; ks < 4; ++ks)
        bfr[nsub][ks] = *(const short8*)(Winb + (n0 + (nsub << 4) + lm) * 128 + ks * 32 + quad * 8);
    float4_t acc[4] = { {0,0,0,0},{0,0,0,0},{0,0,0,0},{0,0,0,0} };
#pragma unroll
    for (int ks = 0; ks < 4; ++ks)
#pragma unroll
      for (int nsub = 0; nsub < 4; ++nsub)
        acc[nsub] = __builtin_amdgcn_mfma_f32_16x16x32_bf16(a[ks], bfr[nsub][ks], acc[nsub], 0, 0, 0);
#pragma unroll
    for (int nsub = 0; nsub < 4; ++nsub) {
      const int n = n0 + (nsub << 4) + lm;
      const float bv = bin[n];
#pragma unroll
      for (int r = 0; r < 4; ++r) {
        const int m = m0 + (quad << 2) + r;
        const int b = m >> 8, t = m & 255;
        ebuf[(((t << 8) | b) << 10) + n] = f2bf(acc[nsub][r] + bv);
      }
    }
  }
}

// Pipelined persistent recurrence. 256 WGs x 512 thr. WG(ns=blk&15: 64 cols, rb=blk>>4:
// 4 rows per chain). Wave q holds W1 AND W2 k-eighth fragments (128 VGPRs). Slot k:
// chain c=k&3, phase m=k>>2; A-frag rows duplicated 4x across lm (coalesced); prefetch
// issued 2 slots ahead, tag-validated at consume; one __syncthreads per slot.
// R7 fix: latch epr into euse at slot start — the k+2 prefetch overwrites epr before the
// epilogue (same parity+phase, chain c+2 slots clobbered it in R6 -> wrong e for rows 0-127).
__global__ __launch_bounds__(512) void rnn_pipe(
    const u16* __restrict__ ebuf, u32* __restrict__ tb0, u32* __restrict__ tb1,
    const u16* __restrict__ W1b, const u16* __restrict__ W2b,
    const float* __restrict__ b1, const float* __restrict__ b2,
    float* __restrict__ fbuf) {
  __shared__ __align__(16) float Pt[2][8][4][68];   // [slot parity][k-eighth][row][col+pad]

  const int tid = threadIdx.x;
  const int q = tid >> 6;                 // wave = k-eighth 0..7
  const int lane = tid & 63, quad = lane >> 4, lm = lane & 15;
  const int rsub = lm & 3;                // data row within 4-row block (lm>=4 duplicate)
  const int ns = blockIdx.x & 15, rb = blockIdx.x >> 4;
  const int n0 = ns << 6;

  // persistent weight fragments, both matrices: B[k][n], lane n=lm, k=quad*8+j
  short8 wf1[4][4], wf2[4][4];            // [nsub][kstep]
#pragma unroll
  for (int nsub = 0; nsub < 4; ++nsub)
#pragma unroll
    for (int ks = 0; ks < 4; ++ks) {
      const int off = ((n0 + (nsub << 4) + lm) << 10) + (q << 7) + (ks << 5) + (quad << 3);
      wf1[nsub][ks] = *(const short8*)(W1b + off);
      wf2[nsub][ks] = *(const short8*)(W2b + off);
    }

  const int me = tid >> 6;                // epilogue row 0..3 (tid<256)
  const int nc = tid & 63;                // epilogue col 0..63
  float bias1 = 0.f, bias2 = 0.f;
  if (tid < 256) { bias1 = b1[n0 + nc]; bias2 = b2[n0 + nc]; }

  u32* tb[2] = { tb0, tb1 };
  u64 pfA[16], pfB[16];
  u16 eprA = 0, eprB = 0;

  for (int k2 = 0; k2 < 2048; k2 += 2) {
#pragma unroll
    for (int par = 0; par < 2; ++par) {
      const int k = k2 + par;
      u64* pf = par ? pfB : pfA;
      u16& epr = par ? eprB : eprA;
      const u16 euse = epr;              // latch slot-k value BEFORE k+2 prefetch clobbers
      const int m = k >> 2, c = k & 3, st = m & 1;
      const int row0 = (c << 6) + (rb << 2);

      // ---- acquire A-fragments ----
      short8 afr[4];
      if (m == 0) {                        // phase 0 input = ebuf[t=0] (plain bf16)
        const u16* rbase = ebuf + ((row0 + rsub) << 10) + (q << 7) + (quad << 3);
#pragma unroll
        for (int ks = 0; ks < 4; ++ks)
          afr[ks] = *(const short8*)(rbase + (ks << 5));
      } else {
        const u32* abase = tb[m & 1] + ((row0 + rsub) << 10) + (q << 7) + (quad << 3);
        const u32 exp = (u32)m;
        u64 v[16];
#pragma unroll
        for (int i = 0; i < 16; ++i) v[i] = pf[i];
        for (;;) {
          u32 bad = 0;
#pragma unroll
          for (int i = 0; i < 16; ++i) {
            const u32 lo = (u32)v[i], hi = (u32)(v[i] >> 32);
            bad |= ((lo ^ exp) | (hi ^ exp)) & 0xffffu;
          }
          if (!__any(bad)) break;
          __builtin_amdgcn_s_sleep(1);
#pragma unroll
          for (int ks = 0; ks < 4; ++ks)
#pragma unroll
            for (int j = 0; j < 4; ++j)
              v[(ks << 2) + j] = __hip_atomic_load(
                  (const u64*)(abase + (ks << 5) + (j << 1)),
                  __ATOMIC_RELAXED, __HIP_MEMORY_SCOPE_AGENT);
        }
#pragma unroll
        for (int ks = 0; ks < 4; ++ks) {
          uint4 pk;
          const u64 v0 = v[(ks << 2) + 0], v1 = v[(ks << 2) + 1];
          const u64 v2 = v[(ks << 2) + 2], v3 = v[(ks << 2) + 3];
          pk.x = ((u32)v0 >> 16) | ((u32)(v0 >> 32) & 0xffff0000u);
          pk.y = ((u32)v1 >> 16) | ((u32)(v1 >> 32) & 0xffff0000u);
          pk.z = ((u32)v2 >> 16) | ((u32)(v2 >> 32) & 0xffff0000u);
          pk.w = ((u32)v3 >> 16) | ((u32)(v3 >> 32) & 0xffff0000u);
          afr[ks] = __builtin_bit_cast(short8, pk);
        }
      }

      // ---- MFMA (16 per wave; rows 4-15 are duplicates) ----
      float4_t acc[4] = { {0,0,0,0},{0,0,0,0},{0,0,0,0},{0,0,0,0} };
      if (!st) {
#pragma unroll
        for (int ks = 0; ks < 4; ++ks)
#pragma unroll
          for (int nsub = 0; nsub < 4; ++nsub)
            acc[nsub] = __builtin_amdgcn_mfma_f32_16x16x32_bf16(afr[ks], wf1[nsub][ks], acc[nsub], 0, 0, 0);
      } else {
#pragma unroll
        for (int ks = 0; ks < 4; ++ks)
#pragma unroll
          for (int nsub = 0; nsub < 4; ++nsub)
            acc[nsub] = __builtin_amdgcn_mfma_f32_16x16x32_bf16(afr[ks], wf2[nsub][ks], acc[nsub], 0, 0, 0);
      }
      if (quad == 0) {                     // rows 0..3 live in quad-0 regs
#pragma unroll
        for (int nsub = 0; nsub < 4; ++nsub)
#pragma unroll
          for (int r = 0; r < 4; ++r)
            Pt[k & 1][q][r][(nsub << 4) + lm] = acc[nsub][r];
      }

      // ---- issue prefetch for slot k+2 ----
      const int kk = k + 2;
      if (kk < 2048) {
        const int m2 = kk >> 2, c2 = kk & 3;
        if (m2 >= 1) {
          const u32* ab2 = tb[m2 & 1] + ((((c2 << 6) + (rb << 2)) + rsub) << 10) + (q << 7) + (quad << 3);
#pragma unroll
          for (int ks = 0; ks < 4; ++ks)
#pragma unroll
            for (int j = 0; j < 4; ++j)
              pf[(ks << 2) + j] = __hip_atomic_load(
                  (const u64*)(ab2 + (ks << 5) + (j << 1)),
                  __ATOMIC_RELAXED, __HIP_MEMORY_SCOPE_AGENT);
        }
        if ((m2 & 1) && m2 < 511 && tid < 256) {   // e(t+1) for slot kk's epilogue
          const int t1 = (m2 >> 1) + 1;
          epr = ebuf[(((t1 << 8) + (c2 << 6) + (rb << 2) + me) << 10) + n0 + nc];
        }
      }

      __syncthreads();

      // ---- epilogue: reduce 8 k-partials, bias, relu, (+e), tagged store ----
      if (tid < 256) {
        float s = st ? bias2 : bias1;
#pragma unroll
        for (int qq = 0; qq < 8; ++qq)
          s += Pt[k & 1][qq][me][nc];
        s = s > 0.f ? s : 0.f;
        const int grow = row0 + me;
        if (m == 511) {
          fbuf[(grow << 10) + n0 + nc] = s;        // final state, fp32
        } else {
          if (st) s += bf2f(euse);
          const u32 w = ((u32)f2bf(s) << 16) | (u32)(m + 1);
          __hip_atomic_store(tb[(m + 1) & 1] + (grow << 10) + n0 + nc, w,
                             __ATOMIC_RELAXED, __HIP_MEMORY_SCOPE_AGENT);
        }
      }
    }
  }
}

__global__ __launch_bounds__(256) void bcast(const float* __restrict__ fbuf,
                                             float* __restrict__ out) {
  const int idx4 = blockIdx.x * 256 + threadIdx.x;   // 0..16777215 float4s
  const int b = idx4 >> 16;
  const int s4 = idx4 & 255;
  const float4_t v = *(const float4_t*)(fbuf + (b << 10) + (s4 << 2));
  *(float4_t*)(out + ((size_t)idx4 << 2)) = v;
}

extern "C" void kernel_launch(void* const* d_in, const int* in_sizes, int n_in,
                              void* d_out, int out_size, void* d_ws, size_t ws_size,
                              hipStream_t stream) {
  const float* x     = (const float*)d_in[0];
  const float* Win   = (const float*)d_in[1];
  const float* bin   = (const float*)d_in[2];
  const float* Wrec  = (const float*)d_in[3];
  const float* brec  = (const float*)d_in[4];
  const float* Wrec2 = (const float*)d_in[5];
  const float* brec2 = (const float*)d_in[6];
  float* out = (float*)d_out;

  char* ws = (char*)d_ws;
  u16* W1b   = (u16*)(ws);                 // 2 MB
  u16* W2b   = (u16*)(ws + (2u << 20));    // 2 MB
  u32* tb0   = (u32*)(ws + (4u << 20));    // 1 MB tagged state (even-phase input)
  u32* tb1   = (u32*)(ws + (5u << 20));    // 1 MB tagged state (odd-phase input)
  float* fbuf = (float*)(ws + (6u << 20)); // 1 MB
  u16* ebuf = (u16*)d_out;                         // 128 MB scratch in d_out
  u16* Winb = (u16*)((char*)d_out + (200u << 20)); // 256 KB scratch in d_out (dead pre-bcast)
  // No init kernels: tags use exact-match on phase 1..511; 0xAAAA/0x0000 never match.

  prep_w<<<4096, 256, 0, stream>>>(Wrec, Wrec2, Win, W1b, W2b, Winb);
  ext_gemm<<<1024, 256, 0, stream>>>(x, Winb, bin, ebuf);

  void* args[] = { (void*)&ebuf, (void*)&tb0, (void*)&tb1, (void*)&W1b, (void*)&W2b,
                   (void*)&brec, (void*)&brec2, (void*)&fbuf };
  (void)hipLaunchCooperativeKernel(reinterpret_cast<void*>(rnn_pipe),
                                   dim3(256), dim3(512), args, 0, stream);

  bcast<<<65536, 256, 0, stream>>>(fbuf, out);
}